// Round 11
// baseline (5685.172 us; speedup 1.0000x reference)
//
#include <hip/hip_runtime.h>
#include <cstdint>
#include <cstddef>

typedef __attribute__((ext_vector_type(8))) short s8v;          // 8 bf16
typedef __attribute__((ext_vector_type(4))) float f4v;
typedef __attribute__((ext_vector_type(4))) unsigned int u4v;

#define DEVFN __device__ __forceinline__

DEVFN unsigned short f2bf(float f) {
    unsigned int u = __builtin_bit_cast(unsigned int, f);
    return (unsigned short)((u + 0x7FFFu + ((u >> 16) & 1u)) >> 16);
}
DEVFN float bf2f(unsigned short h) {
    unsigned int u = ((unsigned int)h) << 16;
    return __builtin_bit_cast(float, u);
}
DEVFN float sigm(float x) { return 1.0f / (1.0f + __expf(-x)); }
DEVFN float tanh_fast(float x) { float e = __expf(2.0f * x); return 1.0f - 2.0f / (e + 1.0f); }

// device-scope (LLC) write-through store — visible across XCDs, no fence.
DEVFN void store_wt(unsigned int* p, unsigned int v) {
    asm volatile("global_store_dword %0, %1, off sc0 sc1"
                 :: "v"(p), "v"(v) : "memory");
}
// LLC-direct flag read + drain (spin path).
DEVFN unsigned poll_load(const unsigned int* p) {
    unsigned v;
    asm volatile("global_load_dword %0, %1, off sc0 sc1\n\t"
                 "s_waitcnt vmcnt(0)"
                 : "=v"(v) : "v"(p) : "memory");
    return v;
}
// fire-and-forget flag read (early-check issue; drained later).
DEVFN void poll_issue(const unsigned int* p, unsigned& v) {
    asm volatile("global_load_dword %0, %1, off sc0 sc1"
                 : "=v"(v) : "v"(p) : "memory");
}
// 8x dwordx4 LLC-direct tile gather + drain.
DEVFN void gather_h(const void* p0, const void* p1,
                    u4v& a0, u4v& a1, u4v& a2, u4v& a3,
                    u4v& a4, u4v& a5, u4v& a6, u4v& a7) {
    asm volatile(
        "global_load_dwordx4 %0, %8, off sc0 sc1\n\t"
        "global_load_dwordx4 %1, %8, off offset:1024 sc0 sc1\n\t"
        "global_load_dwordx4 %2, %8, off offset:2048 sc0 sc1\n\t"
        "global_load_dwordx4 %3, %8, off offset:3072 sc0 sc1\n\t"
        "global_load_dwordx4 %4, %9, off sc0 sc1\n\t"
        "global_load_dwordx4 %5, %9, off offset:1024 sc0 sc1\n\t"
        "global_load_dwordx4 %6, %9, off offset:2048 sc0 sc1\n\t"
        "global_load_dwordx4 %7, %9, off offset:3072 sc0 sc1\n\t"
        "s_waitcnt vmcnt(0)"
        : "=&v"(a0), "=&v"(a1), "=&v"(a2), "=&v"(a3),
          "=&v"(a4), "=&v"(a5), "=&v"(a6), "=&v"(a7)
        : "v"(p0), "v"(p1)
        : "memory");
}

// ---------------- geometry ----------------
constexpr int BB = 32, SS = 1024, II = 512, HH = 1024;
constexpr int NCOL = 6144;

constexpr size_t OFF_X    = 0;                       // bf16 x   [32768][512]
constexpr size_t SZ_X     = (size_t)BB * SS * II * 2;
constexpr size_t OFF_WINT = OFF_X + SZ_X;            // bf16 WinT [6144][512]
constexpr size_t SZ_WINT  = (size_t)NCOL * II * 2;
constexpr size_t OFF_WREC = OFF_WINT + SZ_WINT;      // bf16 Wrec [2][3072][1024]
constexpr size_t SZ_WREC  = (size_t)2 * 3072 * HH * 2;
constexpr size_t OFF_BIAS = OFF_WREC + SZ_WREC;      // f32 [6144]
constexpr size_t SZ_BIAS  = (size_t)NCOL * 4;
// h tiles: [dir][buf][bg][jg(64)][b16(16)][j16(16)] bf16 — 512 B per tile
constexpr size_t OFF_H    = OFF_BIAS + SZ_BIAS;
constexpr size_t SZ_H     = (size_t)2 * 2 * 2 * 64 * 512;
constexpr size_t OFF_BAR  = OFF_H + SZ_H;            // flags [4 groups][64 jg][4 wave]
constexpr size_t SZ_BAR   = 4096;
// G layout (r7): [s][dir][jg(64)][bg(2)][b16(16)][gate(3)][j(16)] bf16
constexpr size_t OFF_G    = OFF_BAR + SZ_BAR;
constexpr size_t SZ_G     = (size_t)SS * BB * NCOL * 2;
constexpr size_t WS_NEED  = OFF_G + SZ_G;            // ~455 MB

// gru_rec LDS layout
constexpr int WL_OFF = 0;          // 98304  weights
constexpr int PL_OFF = 98304;      // 26112  partials x2 parity
constexpr int GR_OFF = 124416;     // 6144   G ring, 4 slots x 1536B
constexpr int PF_OFF = 130560;     // 32     partial flags [2 par][4 wave]
constexpr int RD_OFF = 130592;     // 16     G ring ready[4]
constexpr int PG_OFF = 130608;     // 16     G ring progress[4 wave]
constexpr int OB_OFF = 130624;     // 16384  out buffer [16 steps][256 thr] f32
constexpr int SMEM_TOT = 147008;
constexpr int PLF = 4 * 3 * 16 * 17;   // floats per parity buffer

// =====================================================================
// prep: x->bf16; weight transposes with COALESCED reads.
// =====================================================================
__global__ void prep_kernel(
    const float* __restrict__ x,
    const float* __restrict__ Wi, const float* __restrict__ Wni,
    const float* __restrict__ Winvi, const float* __restrict__ Wninvi,
    const float* __restrict__ Wh, const float* __restrict__ Wnh,
    const float* __restrict__ Winvh, const float* __restrict__ Wninvh,
    const float* __restrict__ Bg, const float* __restrict__ Bni,
    const float* __restrict__ Binv, const float* __restrict__ Bninvi,
    unsigned short* __restrict__ xb, unsigned short* __restrict__ WinT,
    unsigned short* __restrict__ Wrec, float* __restrict__ bias)
{
    typedef __attribute__((ext_vector_type(4))) unsigned int uv4;
    constexpr int NX8 = (BB * SS * II) / 8;
    constexpr int NWI = NCOL * II;
    constexpr int NWR = NCOL * HH;
    constexpr int TOT = NX8 + NWI + NWR + NCOL;
    for (int i = blockIdx.x * blockDim.x + threadIdx.x; i < TOT;
         i += gridDim.x * blockDim.x) {
        if (i < NX8) {
            const float* sp = x + (size_t)i * 8;
            unsigned short o[8];
#pragma unroll
            for (int j = 0; j < 8; ++j) o[j] = f2bf(sp[j]);
            uv4 v;
            v[0] = (unsigned)o[0] | ((unsigned)o[1] << 16);
            v[1] = (unsigned)o[2] | ((unsigned)o[3] << 16);
            v[2] = (unsigned)o[4] | ((unsigned)o[5] << 16);
            v[3] = (unsigned)o[6] | ((unsigned)o[7] << 16);
            *(uv4*)(xb + (size_t)i * 8) = v;
        } else if (i < NX8 + NWI) {
            int u = i - NX8;
            int k = u / NCOL, n = u % NCOL;
            const float* src; int stride, col;
            if (n < 2048)      { src = Wi;     col = n;        stride = 2048; }
            else if (n < 3072) { src = Wni;    col = n - 2048; stride = 1024; }
            else if (n < 5120) { src = Winvi;  col = n - 3072; stride = 2048; }
            else               { src = Wninvi; col = n - 5120; stride = 1024; }
            WinT[(size_t)n * 512 + k] = f2bf(src[(size_t)k * stride + col]);
        } else if (i < NX8 + NWI + NWR) {
            int u = i - NX8 - NWI;
            int k = u / NCOL, R = u % NCOL;
            int dir = R / 3072, rr = R % 3072;
            const float* src; int stride, col;
            if (rr < 2048) { src = dir ? Winvh : Wh;   col = rr;        stride = 2048; }
            else           { src = dir ? Wninvh : Wnh; col = rr - 2048; stride = 1024; }
            Wrec[(size_t)R * 1024 + k] = f2bf(src[(size_t)k * stride + col]);
        } else {
            int c = i - NX8 - NWI - NWR;
            int dir = c / 3072, cc = c % 3072;
            bias[c] = (cc < 2048) ? (dir ? Binv : Bg)[cc]
                                  : (dir ? Bninvi : Bni)[cc - 2048];
        }
    }
}

// =====================================================================
// gemm_in: double-buffered staging; epilogue restaged through LDS into
// r7-layout G with dwordx4 stores (16 B/lane vs 2 B/lane scatter).
// =====================================================================
#define GLL16(gp, lp) __builtin_amdgcn_global_load_lds( \
    (const __attribute__((address_space(1))) void*)(gp), \
    (__attribute__((address_space(3))) void*)(lp), 16, 0, 0)

__global__ __launch_bounds__(256, 2) void gemm_in(
    const unsigned short* __restrict__ xb,
    const unsigned short* __restrict__ WinT,
    const float* __restrict__ bias,
    unsigned short* __restrict__ G)
{
    __shared__ char smem[65536];   // 2 buffers x (16K A + 16K B)
    const int tid = threadIdx.x, lane = tid & 63, wid = tid >> 6;
    int wg = blockIdx.x;
    int swz = (wg & 7) * 1536 + (wg >> 3);   // bijective XCD swizzle
    const int m0 = (swz & 255) * 128, n0 = (swz >> 8) * 128;
    const int l15 = lane & 15, hi = lane >> 4;
    const int mw = (wid & 1) * 64, nw = (wid >> 1) * 64;

    f4v acc[4][4] = {};
    const char* xrow = (const char*)xb;
    const char* wrow = (const char*)WinT;

    auto stage = [&](int buf, int kt) {
        char* As = smem + buf * 32768;
        char* Bs = As + 16384;
        const int kb0 = kt * 128;
#pragma unroll
        for (int r = 0; r < 4; ++r) {
            int q = wid * 4 + r;
            int o = q * 1024 + lane * 16;
            int row = o >> 7;
            int kbs = (o ^ ((row & 7) << 4)) & 127;
            GLL16(xrow + (size_t)(m0 + row) * 1024 + kb0 + kbs, As + q * 1024);
            GLL16(wrow + (size_t)(n0 + row) * 1024 + kb0 + kbs, Bs + q * 1024);
        }
    };

    stage(0, 0);
    __syncthreads();
    int buf = 0;
    for (int kt = 0; kt < 8; ++kt) {
        if (kt < 7) stage(buf ^ 1, kt + 1);
        char* As = smem + buf * 32768;
        char* Bs = As + 16384;
#pragma unroll
        for (int kc = 0; kc < 2; ++kc) {
            s8v a[4], b[4];
#pragma unroll
            for (int mt = 0; mt < 4; ++mt) {
                int row = mw + mt * 16 + l15;
                int off = (row << 7) + kc * 64 + hi * 16;
                a[mt] = *(const s8v*)(As + (off ^ ((row & 7) << 4)));
            }
#pragma unroll
            for (int nt = 0; nt < 4; ++nt) {
                int row = nw + nt * 16 + l15;
                int off = (row << 7) + kc * 64 + hi * 16;
                b[nt] = *(const s8v*)(Bs + (off ^ ((row & 7) << 4)));
            }
#pragma unroll
            for (int mt = 0; mt < 4; ++mt)
#pragma unroll
                for (int nt = 0; nt < 4; ++nt)
                    acc[mt][nt] = __builtin_amdgcn_mfma_f32_16x16x32_bf16(
                        a[mt], b[nt], acc[mt][nt], 0, 0, 0);
        }
        __syncthreads();
        buf ^= 1;
    }

    // ---- epilogue: bf16 restage via LDS, then 16 B/lane stores ----
    {
        unsigned short* cs = (unsigned short*)smem;   // [128 si'][8 jgl][16 j]
#pragma unroll
        for (int mt = 0; mt < 4; ++mt)
#pragma unroll
            for (int rg = 0; rg < 4; ++rg) {
                int sil = mw + mt * 16 + hi * 4 + rg;
#pragma unroll
                for (int nt = 0; nt < 4; ++nt) {
                    int n = n0 + nw + nt * 16 + l15;
                    int jgl = (nw >> 4) + nt;
                    cs[(sil * 8 + jgl) * 16 + l15] =
                        f2bf(acc[mt][nt][rg] + bias[n]);
                }
            }
        __syncthreads();
        const int n_dir = (n0 >= 3072);
        const int rem0 = n0 - n_dir * 3072;
        const int gate = rem0 >> 10;
        const int jg0 = (rem0 & 1023) >> 4;
        const int bi = m0 >> 10;
        const int bgb = bi >> 4, b16 = bi & 15;
        const int si0 = m0 & 1023;
        const char* lbase = (const char*)cs;
#pragma unroll
        for (int r = 0; r < 8; ++r) {
            int uidx = r * 256 + tid;
            int piece = uidx >> 1, half = uidx & 1;
            int sil = piece >> 3, jgl = piece & 7;
            u4v d = *(const u4v*)(lbase + piece * 32 + half * 16);
            size_t gb = (((((size_t)(si0 + sil) * 2 + n_dir) * 64 + (jg0 + jgl))
                          * 2 + bgb) * 16 + b16) * 96 + gate * 32 + half * 16;
            *(u4v*)((char*)G + gb) = d;
        }
    }
}

// =====================================================================
// gru_rec: persistent bidirectional GRU, 256 blocks (1/CU), 320 threads:
// waves 0-3 compute, wave 4 = G prefetcher. r7 targeted poll (16 source
// blocks/wave — race-free via intra-block pflag coupling) + EARLY flag
// check issued at end of prev step; out batched 16 steps in LDS.
// =====================================================================
__global__ __launch_bounds__(320, 1) void gru_rec(
    const unsigned short* __restrict__ G,     // [s][dir][jg][bg][b16][gate][j]
    const unsigned short* __restrict__ Wrec,  // [2][3072][1024]
    const float* __restrict__ Bnh,
    const float* __restrict__ Bninvh,
    unsigned short* __restrict__ hbuf,        // bf16 tiles [dir][buf][bg][jg][16][16]
    float* __restrict__ out,                  // [32][1024][2048] + ht [32][2048]
    unsigned int* __restrict__ flags)         // [4 groups][64 jg][4 wave]
{
    extern __shared__ char smem[];
    char* wl = smem + WL_OFF;
    float* pl = (float*)(smem + PL_OFF);
    unsigned short* gring = (unsigned short*)(smem + GR_OFF);
    volatile int* pflag = (volatile int*)(smem + PF_OFF);
    volatile int* gready = (volatile int*)(smem + RD_OFF);
    volatile int* gprog  = (volatile int*)(smem + PG_OFF);
    float* obuf = (float*)(smem + OB_OFF);    // [16][256]

    const int tid = threadIdx.x, lane = tid & 63, wid = tid >> 6;
    const int bid = blockIdx.x;
    const int dir = bid >> 7, bg = (bid >> 6) & 1, jg = bid & 63;
    const int jbase = jg * 16, bb = bg * 16;
    const int l15 = lane & 15, hi = lane >> 4;
    unsigned int* fl = flags + ((dir * 2 + bg) << 8);

    // ---- prologue: init LDS flags; stage 3 weight panels into LDS ----
    if (tid < 4) { gready[tid] = -1; gprog[tid] = -1; }
    if (tid >= 4 && tid < 12) pflag[tid - 4] = -1;
    if (tid < 256) {
        const char* wsrc = (const char*)Wrec;
        for (int q = 0; q < 24; ++q) {
            int o = (q * 256 + tid) * 16;
            int c = o >> 11;
            int kb = (o ^ ((c & 7) << 4)) & 2047;
            int n = dir * 3072 + (c >> 4) * 1024 + jbase + (c & 15);
            *(u4v*)(wl + o) = *(const u4v*)(wsrc + (size_t)n * 2048 + kb);
        }
    }
    const int b_l = tid >> 4, j_l = tid & 15;
    const float bnh = (dir ? Bninvh : Bnh)[jbase + (j_l & 15)];
    __syncthreads();   // the ONLY block-wide barrier

    const size_t gstride_b = (size_t)2 * 64 * 2 * 768 * 2;   // bytes per s
    const char* gcb = (const char*)G + (((size_t)dir * 64 + jg) * 2 + bg) * 1536;

    if (wid == 4) {
        // ---------------- G prefetch wave (contiguous 1536 B chunk) ----
        char* grb = (char*)gring;
        for (int t = 0; t < 1024; ++t) {
            const int slot = t & 3;
            if (t >= 4) {
                int v;
                do { v = gprog[lane & 3]; } while (!__all(v >= t - 4));
            }
            const int gpos = dir ? (1023 - t) : t;
            const char* src = gcb + (size_t)gpos * gstride_b + lane * 32;
            if (lane < 48) {
                u4v d0 = *(const u4v*)(src);
                u4v d1 = *(const u4v*)(src + 16);
                *(u4v*)(grb + slot * 1536 + lane * 32) = d0;
                *(u4v*)(grb + slot * 1536 + lane * 32 + 16) = d1;
            }
            asm volatile("s_waitcnt lgkmcnt(0) vmcnt(0)" ::: "memory");
            if (lane == 0) gready[slot] = t;
        }
        return;
    }

    // ---------------- compute waves (0..3) ----------------
    float h_old = 0.0f;
    unsigned int* hbuf32 = (unsigned int*)hbuf;
    // targeted poll: wave wid covers jg_l = wid*16 + (lane>>2), wave_p = lane&3
    const unsigned int* fp = fl + wid * 64 + lane;
    const bool self = (wid * 16 + (lane >> 2)) == jg;   // own-block flags:
    // guaranteed by intra-block pflag sync — exempt from the early check.
    unsigned early_v = 0;

    for (int s = 0; s < 1024; ++s) {
        const int par = s & 1;
        float* plc = pl + par * PLF;

        // ---- G for this step from the LDS ring ----
        const int slot = s & 3;
        {
            int r;
            do { r = gready[slot]; } while (r != s);
        }
        asm volatile("" ::: "memory");
        const int gb = slot * 768 + b_l * 48 + j_l;
        unsigned short gr = gring[gb];
        unsigned short gz = gring[gb + 16];
        unsigned short gn = gring[gb + 32];
        asm volatile("s_waitcnt lgkmcnt(0)" ::: "memory");
        if (lane == 0) gprog[wid] = s;

        float rsum = 0.f, zsum = 0.f, nsum = 0.f;
        if (s > 0) {
            const unsigned tgt = (unsigned)s;
            // drain the early-issued flag loads (ties early_v through the wait)
            asm volatile("s_waitcnt vmcnt(0) ; %0" : "+v"(early_v) :: "memory");
            if (!__all(self | (early_v >= tgt))) {
                unsigned v;
                do { v = poll_load(fp); } while (!__all(self | (v >= tgt)));
            }

            // ---- gather h tiles (contiguous 512B per producer block) ----
            const int rbuf = par ^ 1;
            const char* hb = (const char*)hbuf +
                ((((size_t)(dir * 2 + rbuf) * 2 + bg) * 64)
                 + (size_t)(wid * 16 + (hi >> 1))) * 512
                + l15 * 32 + (hi & 1) * 16;
            u4v u[8];
            gather_h(hb, hb + 4096, u[0], u[1], u[2], u[3],
                     u[4], u[5], u[6], u[7]);

            f4v acc[3] = {};
#pragma unroll
            for (int p = 0; p < 3; ++p) {
                int c = p * 16 + l15;
                int cbase = c << 11;
                int sw = (c & 7) << 4;
#pragma unroll
                for (int kc = 0; kc < 8; ++kc) {
                    int off = cbase + (wid << 9) + kc * 64 + hi * 16;
                    s8v bf = *(const s8v*)(wl + (off ^ sw));
                    acc[p] = __builtin_amdgcn_mfma_f32_16x16x32_bf16(
                        __builtin_bit_cast(s8v, u[kc]), bf, acc[p], 0, 0, 0);
                }
            }
#pragma unroll
            for (int p = 0; p < 3; ++p)
#pragma unroll
                for (int rg = 0; rg < 4; ++rg)
                    plc[((wid * 3 + p) * 16 + hi * 4 + rg) * 17 + l15] = acc[p][rg];
            asm volatile("s_waitcnt lgkmcnt(0)" ::: "memory");
            if (lane == 0) pflag[par * 4 + wid] = s;

            // ---- barrier-free reduce sync: wait all 4 compute waves ----
            {
                int f0, f1, f2, f3;
                do {
                    f0 = pflag[par * 4 + 0]; f1 = pflag[par * 4 + 1];
                    f2 = pflag[par * 4 + 2]; f3 = pflag[par * 4 + 3];
                } while (f0 < s || f1 < s || f2 < s || f3 < s);
            }
            asm volatile("" ::: "memory");
#pragma unroll
            for (int w = 0; w < 4; ++w) {
                rsum += plc[((w * 3 + 0) * 16 + b_l) * 17 + j_l];
                zsum += plc[((w * 3 + 1) * 16 + b_l) * 17 + j_l];
                nsum += plc[((w * 3 + 2) * 16 + b_l) * 17 + j_l];
            }
        }

        float rv = sigm(rsum + bf2f(gr));
        float zv = sigm(zsum + bf2f(gz));
        float nv = tanh_fast(bf2f(gn) + rv * (nsum + bnh));
        float hn = (1.0f - zv) * nv + zv * h_old;
        h_old = hn;

        if (s < 1023) {
            // h tile store (contiguous 512B, write-through pairs) ...
            unsigned short hbv = f2bf(hn);
            unsigned int other = (unsigned int)(unsigned short)__shfl_xor((int)hbv, 1);
            if (!(tid & 1)) {
                size_t w32 = ((((size_t)(dir * 2 + par) * 2 + bg) * 64 + jg) * 128)
                             + b_l * 8 + (j_l >> 1);
                store_wt(hbuf32 + w32, (unsigned)hbv | (other << 16));
            }
            // drain ONLY h stores, publish flag, then ISSUE next step's
            // flag loads (in flight across the loop backedge).
            asm volatile("s_waitcnt vmcnt(0)" ::: "memory");
            if (lane == 0)
                store_wt(&fl[jg * 4 + wid], (unsigned)(s + 1));
            poll_issue(fp, early_v);
        }

        // out: buffer in LDS; flush every 16 steps (acks overlap next polls)
        obuf[(s & 15) * 256 + tid] = hn;
        if ((s & 15) == 15) {
            const int s0 = s - 15;
#pragma unroll
            for (int k = 0; k < 16; ++k) {
                float v = obuf[k * 256 + tid];
                int st = s0 + k;
                int s_out = dir ? (1023 - st) : st;
                __builtin_nontemporal_store(v,
                    &out[((size_t)(bb + b_l) * SS + s_out) * 2048
                         + dir * 1024 + jbase + j_l]);
            }
        }
        if (s == 1023)
            __builtin_nontemporal_store(hn,
                &out[(size_t)BB * SS * 2048 + (size_t)(bb + b_l) * 2048 +
                     dir * 1024 + jbase + j_l]);
    }
}

// =====================================================================
extern "C" void kernel_launch(void* const* d_in, const int* in_sizes, int n_in,
                              void* d_out, int out_size, void* d_ws, size_t ws_size,
                              hipStream_t stream)
{
    if (n_in < 15) return;
    const float* x      = (const float*)d_in[0];
    const float* Wi     = (const float*)d_in[1];
    const float* Wh     = (const float*)d_in[2];
    const float* Bg     = (const float*)d_in[3];
    const float* Wni    = (const float*)d_in[4];
    const float* Wnh    = (const float*)d_in[5];
    const float* Bni    = (const float*)d_in[6];
    const float* Bnh    = (const float*)d_in[7];
    const float* Winvi  = (const float*)d_in[8];
    const float* Winvh  = (const float*)d_in[9];
    const float* Binv   = (const float*)d_in[10];
    const float* Wninvi = (const float*)d_in[11];
    const float* Wninvh = (const float*)d_in[12];
    const float* Bninvi = (const float*)d_in[13];
    const float* Bninvh = (const float*)d_in[14];

    if (ws_size < WS_NEED) {
        hipMemsetAsync(d_out, 0, (size_t)out_size * 4, stream);
        return;
    }
    char* ws = (char*)d_ws;
    unsigned short* xb   = (unsigned short*)(ws + OFF_X);
    unsigned short* WinT = (unsigned short*)(ws + OFF_WINT);
    unsigned short* Wrec = (unsigned short*)(ws + OFF_WREC);
    float*          bias = (float*)(ws + OFF_BIAS);
    unsigned short* hbuf = (unsigned short*)(ws + OFF_H);
    unsigned int*   bar  = (unsigned int*)(ws + OFF_BAR);
    unsigned short* G    = (unsigned short*)(ws + OFF_G);

    hipMemsetAsync(ws + OFF_BAR, 0, SZ_BAR, stream);

    prep_kernel<<<4096, 256, 0, stream>>>(
        x, Wi, Wni, Winvi, Wninvi, Wh, Wnh, Winvh, Wninvh,
        Bg, Bni, Binv, Bninvi, xb, WinT, Wrec, bias);

    gemm_in<<<12288, 256, 0, stream>>>(xb, WinT, bias, G);

    hipFuncSetAttribute(reinterpret_cast<const void*>(&gru_rec),
                        hipFuncAttributeMaxDynamicSharedMemorySize, SMEM_TOT);
    gru_rec<<<256, 320, SMEM_TOT, stream>>>(
        G, Wrec, Bnh, Bninvh, hbuf, (float*)d_out, bar);
}

// Round 12
// 5196.651 us; speedup vs baseline: 1.0940x; 1.0940x over previous
//
#include <hip/hip_runtime.h>
#include <cstdint>
#include <cstddef>

typedef __attribute__((ext_vector_type(8))) short s8v;          // 8 bf16
typedef __attribute__((ext_vector_type(4))) float f4v;
typedef __attribute__((ext_vector_type(4))) unsigned int u4v;

#define DEVFN __device__ __forceinline__

DEVFN unsigned short f2bf(float f) {
    unsigned int u = __builtin_bit_cast(unsigned int, f);
    return (unsigned short)((u + 0x7FFFu + ((u >> 16) & 1u)) >> 16);
}
DEVFN float bf2f(unsigned short h) {
    unsigned int u = ((unsigned int)h) << 16;
    return __builtin_bit_cast(float, u);
}
DEVFN float sigm(float x) { return 1.0f / (1.0f + __expf(-x)); }
DEVFN float tanh_fast(float x) { float e = __expf(2.0f * x); return 1.0f - 2.0f / (e + 1.0f); }

DEVFN u4v pack8(const unsigned short o[8]) {
    u4v v;
    v[0] = (unsigned)o[0] | ((unsigned)o[1] << 16);
    v[1] = (unsigned)o[2] | ((unsigned)o[3] << 16);
    v[2] = (unsigned)o[4] | ((unsigned)o[5] << 16);
    v[3] = (unsigned)o[6] | ((unsigned)o[7] << 16);
    return v;
}

// device-scope (LLC) write-through store — visible across XCDs, no fence.
DEVFN void store_wt(unsigned int* p, unsigned int v) {
    asm volatile("global_store_dword %0, %1, off sc0 sc1"
                 :: "v"(p), "v"(v) : "memory");
}
// LLC-direct flag read (bypasses stale L1/L2).
DEVFN unsigned poll_load(const unsigned int* p) {
    unsigned v;
    asm volatile("global_load_dword %0, %1, off sc0 sc1\n\t"
                 "s_waitcnt vmcnt(0)"
                 : "=v"(v) : "v"(p) : "memory");
    return v;
}
// 8x dwordx4 LLC-direct tile gather + drain.
DEVFN void gather_h(const void* p0, const void* p1,
                    u4v& a0, u4v& a1, u4v& a2, u4v& a3,
                    u4v& a4, u4v& a5, u4v& a6, u4v& a7) {
    asm volatile(
        "global_load_dwordx4 %0, %8, off sc0 sc1\n\t"
        "global_load_dwordx4 %1, %8, off offset:1024 sc0 sc1\n\t"
        "global_load_dwordx4 %2, %8, off offset:2048 sc0 sc1\n\t"
        "global_load_dwordx4 %3, %8, off offset:3072 sc0 sc1\n\t"
        "global_load_dwordx4 %4, %9, off sc0 sc1\n\t"
        "global_load_dwordx4 %5, %9, off offset:1024 sc0 sc1\n\t"
        "global_load_dwordx4 %6, %9, off offset:2048 sc0 sc1\n\t"
        "global_load_dwordx4 %7, %9, off offset:3072 sc0 sc1\n\t"
        "s_waitcnt vmcnt(0)"
        : "=&v"(a0), "=&v"(a1), "=&v"(a2), "=&v"(a3),
          "=&v"(a4), "=&v"(a5), "=&v"(a6), "=&v"(a7)
        : "v"(p0), "v"(p1)
        : "memory");
}

// ---------------- geometry ----------------
constexpr int BB = 32, SS = 1024, II = 512, HH = 1024;
constexpr int NCOL = 6144;

constexpr size_t OFF_X    = 0;                       // bf16 x   [32768][512]
constexpr size_t SZ_X     = (size_t)BB * SS * II * 2;
constexpr size_t OFF_WINT = OFF_X + SZ_X;            // bf16 WinT [6144][512]
constexpr size_t SZ_WINT  = (size_t)NCOL * II * 2;
constexpr size_t OFF_WREC = OFF_WINT + SZ_WINT;      // bf16 Wrec [2][3072][1024]
constexpr size_t SZ_WREC  = (size_t)2 * 3072 * HH * 2;
constexpr size_t OFF_BIAS = OFF_WREC + SZ_WREC;      // f32 [6144]
constexpr size_t SZ_BIAS  = (size_t)NCOL * 4;
// h tiles: [dir][buf][bg][jg(64)][b16(16)][j16(16)] bf16 — 512 B per tile
constexpr size_t OFF_H    = OFF_BIAS + SZ_BIAS;
constexpr size_t SZ_H     = (size_t)2 * 2 * 2 * 64 * 512;
constexpr size_t OFF_BAR  = OFF_H + SZ_H;            // flags [4 groups][64 jg]
constexpr size_t SZ_BAR   = 4096;
// G layout (r7): [s][dir][jg(64)][bg(2)][b16(16)][gate(3)][j(16)] bf16
constexpr size_t OFF_G    = OFF_BAR + SZ_BAR;
constexpr size_t SZ_G     = (size_t)SS * BB * NCOL * 2;
constexpr size_t WS_NEED  = OFF_G + SZ_G;            // ~455 MB

// gru_rec LDS layout
constexpr int WL_OFF = 0;          // 98304  weights
constexpr int PL_OFF = 98304;      // 26112  partials x2 parity
constexpr int GR_OFF = 124416;     // 6144   G ring, 4 slots x 1536B
constexpr int PF_OFF = 130560;     // 32     partial flags [2 par][4 wave]
constexpr int RD_OFF = 130592;     // 16     G ring ready[4]
constexpr int PG_OFF = 130608;     // 16     G ring progress[4 wave]
constexpr int TF_OFF = 130624;     // 16     tail flags [4 compute waves]
constexpr int HR_OFF = 130640;     // 16     hready (LDS-published by wave 5)
constexpr int SMEM_TOT = 130656;
constexpr int PLF = 4 * 3 * 16 * 17;   // floats per parity buffer

// =====================================================================
// prep (r7 verbatim — reads are lane-coalesced already)
// =====================================================================
__global__ void prep_kernel(
    const float* __restrict__ x,
    const float* __restrict__ Wi, const float* __restrict__ Wni,
    const float* __restrict__ Winvi, const float* __restrict__ Wninvi,
    const float* __restrict__ Wh, const float* __restrict__ Wnh,
    const float* __restrict__ Winvh, const float* __restrict__ Wninvh,
    const float* __restrict__ Bg, const float* __restrict__ Bni,
    const float* __restrict__ Binv, const float* __restrict__ Bninvi,
    unsigned short* __restrict__ xb, unsigned short* __restrict__ WinT,
    unsigned short* __restrict__ Wrec, float* __restrict__ bias)
{
    constexpr int NX8  = (BB * SS * II) / 8;
    constexpr int NWI8 = (NCOL * II) / 8;
    constexpr int NWR8 = (2 * 3072 * HH) / 8;
    constexpr int TOT  = NX8 + NWI8 + NWR8 + NCOL;
    for (int i = blockIdx.x * blockDim.x + threadIdx.x; i < TOT;
         i += gridDim.x * blockDim.x) {
        if (i < NX8) {
            const float* sp = x + (size_t)i * 8;
            unsigned short o[8];
#pragma unroll
            for (int j = 0; j < 8; ++j) o[j] = f2bf(sp[j]);
            *(u4v*)(xb + (size_t)i * 8) = pack8(o);
        } else if (i < NX8 + NWI8) {
            int u = i - NX8;
            int n = u >> 6, k0 = (u & 63) * 8;
            const float* src; int stride;
            if (n < 2048)      { src = Wi + n;            stride = 2048; }
            else if (n < 3072) { src = Wni + (n - 2048);  stride = 1024; }
            else if (n < 5120) { src = Winvi + (n - 3072); stride = 2048; }
            else               { src = Wninvi + (n - 5120); stride = 1024; }
            unsigned short o[8];
#pragma unroll
            for (int j = 0; j < 8; ++j) o[j] = f2bf(src[(size_t)(k0 + j) * stride]);
            *(u4v*)(WinT + (size_t)n * 512 + k0) = pack8(o);
        } else if (i < NX8 + NWI8 + NWR8) {
            int u = i - NX8 - NWI8;
            int R = u >> 7, k0 = (u & 127) * 8;
            int dir = R / 3072, n = R % 3072;
            const float* src; int stride;
            if (n < 2048) { src = (dir ? Winvh : Wh) + n;          stride = 2048; }
            else          { src = (dir ? Wninvh : Wnh) + (n - 2048); stride = 1024; }
            unsigned short o[8];
#pragma unroll
            for (int j = 0; j < 8; ++j) o[j] = f2bf(src[(size_t)(k0 + j) * stride]);
            *(u4v*)(Wrec + (size_t)R * 1024 + k0) = pack8(o);
        } else {
            int c = i - NX8 - NWI8 - NWR8;
            int dir = c / 3072, cc = c % 3072;
            bias[c] = (cc < 2048) ? (dir ? Binv : Bg)[cc]
                                  : (dir ? Bninvi : Bni)[cc - 2048];
        }
    }
}

// =====================================================================
// gemm_in (r7 verbatim)
// =====================================================================
#define GLL16(gp, lp) __builtin_amdgcn_global_load_lds( \
    (const __attribute__((address_space(1))) void*)(gp), \
    (__attribute__((address_space(3))) void*)(lp), 16, 0, 0)

__global__ __launch_bounds__(256, 2) void gemm_in(
    const unsigned short* __restrict__ xb,
    const unsigned short* __restrict__ WinT,
    const float* __restrict__ bias,
    unsigned short* __restrict__ G)
{
    __shared__ char smem[32768];
    char* As = smem;
    char* Bs = smem + 16384;
    const int tid = threadIdx.x, lane = tid & 63, wid = tid >> 6;
    int wg = blockIdx.x;
    int swz = (wg & 7) * 1536 + (wg >> 3);
    const int m0 = (swz & 255) * 128, n0 = (swz >> 8) * 128;
    const int l15 = lane & 15, hi = lane >> 4;
    const int mw = (wid & 1) * 64, nw = (wid >> 1) * 64;

    f4v acc[4][4] = {};

    const char* xrow = (const char*)xb;
    const char* wrow = (const char*)WinT;

    for (int kt = 0; kt < 8; ++kt) {
        const int kb0 = kt * 128;
#pragma unroll
        for (int r = 0; r < 4; ++r) {
            int q = wid * 4 + r;
            int o = q * 1024 + lane * 16;
            int row = o >> 7;
            int kbs = (o ^ ((row & 7) << 4)) & 127;
            GLL16(xrow + (size_t)(m0 + row) * 1024 + kb0 + kbs, As + q * 1024);
            GLL16(wrow + (size_t)(n0 + row) * 1024 + kb0 + kbs, Bs + q * 1024);
        }
        __syncthreads();
#pragma unroll
        for (int kc = 0; kc < 2; ++kc) {
            s8v a[4], b[4];
#pragma unroll
            for (int mt = 0; mt < 4; ++mt) {
                int row = mw + mt * 16 + l15;
                int off = (row << 7) + kc * 64 + hi * 16;
                a[mt] = *(const s8v*)(As + (off ^ ((row & 7) << 4)));
            }
#pragma unroll
            for (int nt = 0; nt < 4; ++nt) {
                int row = nw + nt * 16 + l15;
                int off = (row << 7) + kc * 64 + hi * 16;
                b[nt] = *(const s8v*)(Bs + (off ^ ((row & 7) << 4)));
            }
#pragma unroll
            for (int mt = 0; mt < 4; ++mt)
#pragma unroll
                for (int nt = 0; nt < 4; ++nt)
                    acc[mt][nt] = __builtin_amdgcn_mfma_f32_16x16x32_bf16(
                        a[mt], b[nt], acc[mt][nt], 0, 0, 0);
        }
        __syncthreads();
    }
#pragma unroll
    for (int mt = 0; mt < 4; ++mt) {
#pragma unroll
        for (int rg = 0; rg < 4; ++rg) {
            int m = m0 + mw + mt * 16 + hi * 4 + rg;
            int bi = m >> 10, si = m & 1023;
            int bg = bi >> 4, b16 = bi & 15;
#pragma unroll
            for (int nt = 0; nt < 4; ++nt) {
                int n = n0 + nw + nt * 16 + l15;
                int dir = (n >= 3072);
                int rem = n - dir * 3072;
                int gate = rem >> 10, col = rem & 1023;
                int jg = col >> 4, j = col & 15;
                size_t idx = (((((size_t)si * 2 + dir) * 64 + jg) * 2 + bg) * 16
                              + b16) * 48 + gate * 16 + j;
                G[idx] = f2bf(acc[mt][nt][rg] + bias[n]);
            }
        }
    }
}

// =====================================================================
// gru_rec: persistent bidirectional GRU, 256 blocks (1/CU), 384 threads:
// waves 0-3 compute, wave 4 = G prefetcher, wave 5 = FLAG MANAGER.
// Compute waves touch NO global flags: tail = {h store, vmcnt(0), LDS
// tailflag}; step-start wait = LDS hready spin. Wave 5: waits 4 tailflags,
// stores ONE per-block flag (sc0sc1), tight-polls the 64 group flags,
// publishes hready to LDS. Flag traffic /4 vs r7; poll off compute chain.
// =====================================================================
__global__ __launch_bounds__(384, 1) void gru_rec(
    const unsigned short* __restrict__ G,     // [s][dir][jg][bg][b16][gate][j]
    const unsigned short* __restrict__ Wrec,  // [2][3072][1024]
    const float* __restrict__ Bnh,
    const float* __restrict__ Bninvh,
    unsigned short* __restrict__ hbuf,        // bf16 tiles [dir][buf][bg][jg][16][16]
    float* __restrict__ out,                  // [32][1024][2048] + ht [32][2048]
    unsigned int* __restrict__ flags)         // [4 groups][64 jg]
{
    extern __shared__ char smem[];
    char* wl = smem + WL_OFF;
    float* pl = (float*)(smem + PL_OFF);
    unsigned short* gring = (unsigned short*)(smem + GR_OFF);
    volatile int* pflag = (volatile int*)(smem + PF_OFF);
    volatile int* gready = (volatile int*)(smem + RD_OFF);
    volatile int* gprog  = (volatile int*)(smem + PG_OFF);
    volatile int* tailflag = (volatile int*)(smem + TF_OFF);
    volatile int* hready = (volatile int*)(smem + HR_OFF);

    const int tid = threadIdx.x, lane = tid & 63, wid = tid >> 6;
    const int bid = blockIdx.x;
    const int dir = bid >> 7, bg = (bid >> 6) & 1, jg = bid & 63;
    const int jbase = jg * 16, bb = bg * 16;
    const int l15 = lane & 15, hi = lane >> 4;
    unsigned int* fl = flags + ((dir * 2 + bg) << 6);

    // ---- prologue: init LDS flags; stage 3 weight panels into LDS ----
    if (tid < 4) { gready[tid] = -1; gprog[tid] = -1; }
    if (tid >= 4 && tid < 12) pflag[tid - 4] = -1;
    if (tid >= 12 && tid < 16) tailflag[tid - 12] = -1;
    if (tid == 16) hready[0] = 0;
    if (tid < 256) {
        const char* wsrc = (const char*)Wrec;
        for (int q = 0; q < 24; ++q) {
            int o = (q * 256 + tid) * 16;
            int c = o >> 11;
            int kb = (o ^ ((c & 7) << 4)) & 2047;
            int n = dir * 3072 + (c >> 4) * 1024 + jbase + (c & 15);
            *(u4v*)(wl + o) = *(const u4v*)(wsrc + (size_t)n * 2048 + kb);
        }
    }
    const int b_l = tid >> 4, j_l = tid & 15;
    const float bnh = (dir ? Bninvh : Bnh)[jbase + (j_l & 15)];
    __syncthreads();   // the ONLY block-wide barrier

    const size_t gstride_b = (size_t)2 * 64 * 2 * 768 * 2;   // bytes per s
    const char* gcb = (const char*)G + (((size_t)dir * 64 + jg) * 2 + bg) * 1536;

    if (wid == 4) {
        // ---------------- G prefetch wave (contiguous 1536 B chunk) ----
        char* grb = (char*)gring;
        for (int t = 0; t < 1024; ++t) {
            const int slot = t & 3;
            if (t >= 4) {
                int v;
                do { v = gprog[lane & 3]; } while (!__all(v >= t - 4));
            }
            const int gpos = dir ? (1023 - t) : t;
            const char* src = gcb + (size_t)gpos * gstride_b + lane * 32;
            if (lane < 48) {
                u4v d0 = *(const u4v*)(src);
                u4v d1 = *(const u4v*)(src + 16);
                *(u4v*)(grb + slot * 1536 + lane * 32) = d0;
                *(u4v*)(grb + slot * 1536 + lane * 32 + 16) = d1;
            }
            asm volatile("s_waitcnt lgkmcnt(0) vmcnt(0)" ::: "memory");
            if (lane == 0) gready[slot] = t;
        }
        return;
    }

    if (wid == 5) {
        // ---------------- flag-manager wave ----------------
        // F = t+1 means "this block's h(t) is stored and LLC-visible".
        unsigned int* myflag = &fl[jg];
        const unsigned int* fp = fl + lane;       // all 64 group flags
        for (int t = 0; t < 1023; ++t) {
            int t0, t1, t2, t3;
            do {
                t0 = tailflag[0]; t1 = tailflag[1];
                t2 = tailflag[2]; t3 = tailflag[3];
            } while (t0 < t || t1 < t || t2 < t || t3 < t);
            asm volatile("" ::: "memory");
            if (lane == 0) store_wt(myflag, (unsigned)(t + 1));
            const unsigned tgt = (unsigned)(t + 1);
            unsigned v;
            do { v = poll_load(fp); } while (!__all(v >= tgt));
            hready[0] = t + 1;                    // LDS publish to compute waves
        }
        return;
    }

    // ---------------- compute waves (0..3) ----------------
    float h_old = 0.0f;
    unsigned int* hbuf32 = (unsigned int*)hbuf;

    for (int s = 0; s < 1024; ++s) {
        const int par = s & 1;
        float* plc = pl + par * PLF;

        // ---- G for this step from the LDS ring ----
        const int slot = s & 3;
        {
            int r;
            do { r = gready[slot]; } while (r != s);
        }
        asm volatile("" ::: "memory");
        const int gb = slot * 768 + b_l * 48 + j_l;
        unsigned short gr = gring[gb];
        unsigned short gz = gring[gb + 16];
        unsigned short gn = gring[gb + 32];
        asm volatile("s_waitcnt lgkmcnt(0)" ::: "memory");
        if (lane == 0) gprog[wid] = s;

        float rsum = 0.f, zsum = 0.f, nsum = 0.f;
        if (s > 0) {
            // ---- LDS wait: wave 5 has verified all 64 blocks' h(s-1) ----
            {
                int r;
                do { r = hready[0]; } while (r < s);
            }
            asm volatile("" ::: "memory");

            // ---- gather h tiles (contiguous 512B per producer block) ----
            const int rbuf = par ^ 1;
            const char* hb = (const char*)hbuf +
                ((((size_t)(dir * 2 + rbuf) * 2 + bg) * 64)
                 + (size_t)(wid * 16 + (hi >> 1))) * 512
                + l15 * 32 + (hi & 1) * 16;
            u4v u[8];
            gather_h(hb, hb + 4096, u[0], u[1], u[2], u[3],
                     u[4], u[5], u[6], u[7]);

            f4v acc[3] = {};
#pragma unroll
            for (int p = 0; p < 3; ++p) {
                int c = p * 16 + l15;
                int cbase = c << 11;
                int sw = (c & 7) << 4;
#pragma unroll
                for (int kc = 0; kc < 8; ++kc) {
                    int off = cbase + (wid << 9) + kc * 64 + hi * 16;
                    s8v bf = *(const s8v*)(wl + (off ^ sw));
                    acc[p] = __builtin_amdgcn_mfma_f32_16x16x32_bf16(
                        __builtin_bit_cast(s8v, u[kc]), bf, acc[p], 0, 0, 0);
                }
            }
#pragma unroll
            for (int p = 0; p < 3; ++p)
#pragma unroll
                for (int rg = 0; rg < 4; ++rg)
                    plc[((wid * 3 + p) * 16 + hi * 4 + rg) * 17 + l15] = acc[p][rg];
            asm volatile("s_waitcnt lgkmcnt(0)" ::: "memory");
            if (lane == 0) pflag[par * 4 + wid] = s;

            // ---- barrier-free reduce sync: wait all 4 compute waves ----
            {
                int f0, f1, f2, f3;
                do {
                    f0 = pflag[par * 4 + 0]; f1 = pflag[par * 4 + 1];
                    f2 = pflag[par * 4 + 2]; f3 = pflag[par * 4 + 3];
                } while (f0 < s || f1 < s || f2 < s || f3 < s);
            }
            asm volatile("" ::: "memory");
#pragma unroll
            for (int w = 0; w < 4; ++w) {
                rsum += plc[((w * 3 + 0) * 16 + b_l) * 17 + j_l];
                zsum += plc[((w * 3 + 1) * 16 + b_l) * 17 + j_l];
                nsum += plc[((w * 3 + 2) * 16 + b_l) * 17 + j_l];
            }
        }

        float rv = sigm(rsum + bf2f(gr));
        float zv = sigm(zsum + bf2f(gz));
        float nv = tanh_fast(bf2f(gn) + rv * (nsum + bnh));
        float hn = (1.0f - zv) * nv + zv * h_old;
        h_old = hn;

        if (s < 1023) {
            // h tile store (contiguous 512B, write-through pairs) ...
            unsigned short hbv = f2bf(hn);
            unsigned int other = (unsigned int)(unsigned short)__shfl_xor((int)hbv, 1);
            if (!(tid & 1)) {
                size_t w32 = ((((size_t)(dir * 2 + par) * 2 + bg) * 64 + jg) * 128)
                             + b_l * 8 + (j_l >> 1);
                store_wt(hbuf32 + w32, (unsigned)hbv | (other << 16));
            }
            // drain h stores (LLC ack), then hand off to wave 5 via LDS.
            asm volatile("s_waitcnt vmcnt(0)" ::: "memory");
            if (lane == 0) tailflag[wid] = s;
        }

        // out: nontemporal store after handoff — ack drains during the next
        // step's gather (off the detect path, which now lives in wave 5).
        const int s_out = dir ? (1023 - s) : s;
        __builtin_nontemporal_store(hn,
            &out[((size_t)(bb + b_l) * SS + s_out) * 2048 + dir * 1024 + jbase + j_l]);
        if (s == 1023)
            __builtin_nontemporal_store(hn,
                &out[(size_t)BB * SS * 2048 + (size_t)(bb + b_l) * 2048 +
                     dir * 1024 + jbase + j_l]);
    }
}

// =====================================================================
extern "C" void kernel_launch(void* const* d_in, const int* in_sizes, int n_in,
                              void* d_out, int out_size, void* d_ws, size_t ws_size,
                              hipStream_t stream)
{
    if (n_in < 15) return;
    const float* x      = (const float*)d_in[0];
    const float* Wi     = (const float*)d_in[1];
    const float* Wh     = (const float*)d_in[2];
    const float* Bg     = (const float*)d_in[3];
    const float* Wni    = (const float*)d_in[4];
    const float* Wnh    = (const float*)d_in[5];
    const float* Bni    = (const float*)d_in[6];
    const float* Bnh    = (const float*)d_in[7];
    const float* Winvi  = (const float*)d_in[8];
    const float* Winvh  = (const float*)d_in[9];
    const float* Binv   = (const float*)d_in[10];
    const float* Wninvi = (const float*)d_in[11];
    const float* Wninvh = (const float*)d_in[12];
    const float* Bninvi = (const float*)d_in[13];
    const float* Bninvh = (const float*)d_in[14];

    if (ws_size < WS_NEED) {
        hipMemsetAsync(d_out, 0, (size_t)out_size * 4, stream);
        return;
    }
    char* ws = (char*)d_ws;
    unsigned short* xb   = (unsigned short*)(ws + OFF_X);
    unsigned short* WinT = (unsigned short*)(ws + OFF_WINT);
    unsigned short* Wrec = (unsigned short*)(ws + OFF_WREC);
    float*          bias = (float*)(ws + OFF_BIAS);
    unsigned short* hbuf = (unsigned short*)(ws + OFF_H);
    unsigned int*   bar  = (unsigned int*)(ws + OFF_BAR);
    unsigned short* G    = (unsigned short*)(ws + OFF_G);

    hipMemsetAsync(ws + OFF_BAR, 0, SZ_BAR, stream);

    prep_kernel<<<4096, 256, 0, stream>>>(
        x, Wi, Wni, Winvi, Wninvi, Wh, Wnh, Winvh, Wninvh,
        Bg, Bni, Binv, Bninvi, xb, WinT, Wrec, bias);

    gemm_in<<<12288, 256, 0, stream>>>(xb, WinT, bias, G);

    hipFuncSetAttribute(reinterpret_cast<const void*>(&gru_rec),
                        hipFuncAttributeMaxDynamicSharedMemorySize, SMEM_TOT);
    gru_rec<<<256, 384, SMEM_TOT, stream>>>(
        G, Wrec, Bnh, Bninvh, hbuf, (float*)d_out, bar);
}

// Round 13
// 3897.474 us; speedup vs baseline: 1.4587x; 1.3333x over previous
//
#include <hip/hip_runtime.h>
#include <cstdint>
#include <cstddef>

typedef __attribute__((ext_vector_type(8))) short s8v;          // 8 bf16
typedef __attribute__((ext_vector_type(4))) float f4v;
typedef __attribute__((ext_vector_type(4))) unsigned int u4v;

#define DEVFN __device__ __forceinline__

DEVFN unsigned short f2bf(float f) {
    unsigned int u = __builtin_bit_cast(unsigned int, f);
    return (unsigned short)((u + 0x7FFFu + ((u >> 16) & 1u)) >> 16);
}
DEVFN float bf2f(unsigned short h) {
    unsigned int u = ((unsigned int)h) << 16;
    return __builtin_bit_cast(float, u);
}
DEVFN float sigm(float x) { return 1.0f / (1.0f + __expf(-x)); }
DEVFN float tanh_fast(float x) { float e = __expf(2.0f * x); return 1.0f - 2.0f / (e + 1.0f); }

DEVFN u4v pack8(const unsigned short o[8]) {
    u4v v;
    v[0] = (unsigned)o[0] | ((unsigned)o[1] << 16);
    v[1] = (unsigned)o[2] | ((unsigned)o[3] << 16);
    v[2] = (unsigned)o[4] | ((unsigned)o[5] << 16);
    v[3] = (unsigned)o[6] | ((unsigned)o[7] << 16);
    return v;
}

// device-scope (LLC) write-through store — visible across XCDs, no fence.
DEVFN void store_wt(unsigned int* p, unsigned int v) {
    asm volatile("global_store_dword %0, %1, off sc0 sc1"
                 :: "v"(p), "v"(v) : "memory");
}
// fire-and-forget LLC-direct flag read (completion via pinned waitcnt).
DEVFN void poll_issue(const unsigned int* p, unsigned& v) {
    asm volatile("global_load_dword %0, %1, off sc0 sc1"
                 : "=v"(v) : "v"(p) : "memory");
}
// 8x dwordx4 LLC-direct tile gather + drain. pin0/pin1 keep the spin's
// stray poll registers alive through this asm so the trailing vmcnt(0)
// drains them before their registers can be reused (clobber safety).
DEVFN void gather_h(const void* p0, const void* p1,
                    u4v& a0, u4v& a1, u4v& a2, u4v& a3,
                    u4v& a4, u4v& a5, u4v& a6, u4v& a7,
                    unsigned& pin0, unsigned& pin1) {
    asm volatile(
        "global_load_dwordx4 %0, %10, off sc0 sc1\n\t"
        "global_load_dwordx4 %1, %10, off offset:1024 sc0 sc1\n\t"
        "global_load_dwordx4 %2, %10, off offset:2048 sc0 sc1\n\t"
        "global_load_dwordx4 %3, %10, off offset:3072 sc0 sc1\n\t"
        "global_load_dwordx4 %4, %11, off sc0 sc1\n\t"
        "global_load_dwordx4 %5, %11, off offset:1024 sc0 sc1\n\t"
        "global_load_dwordx4 %6, %11, off offset:2048 sc0 sc1\n\t"
        "global_load_dwordx4 %7, %11, off offset:3072 sc0 sc1\n\t"
        "s_waitcnt vmcnt(0)"
        : "=&v"(a0), "=&v"(a1), "=&v"(a2), "=&v"(a3),
          "=&v"(a4), "=&v"(a5), "=&v"(a6), "=&v"(a7),
          "+v"(pin0), "+v"(pin1)
        : "v"(p0), "v"(p1)
        : "memory");
}

// ---------------- geometry ----------------
constexpr int BB = 32, SS = 1024, II = 512, HH = 1024;
constexpr int NCOL = 6144;

constexpr size_t OFF_X    = 0;                       // bf16 x   [32768][512]
constexpr size_t SZ_X     = (size_t)BB * SS * II * 2;
constexpr size_t OFF_WINT = OFF_X + SZ_X;            // bf16 WinT [6144][512]
constexpr size_t SZ_WINT  = (size_t)NCOL * II * 2;
constexpr size_t OFF_WREC = OFF_WINT + SZ_WINT;      // bf16 Wrec [2][3072][1024]
constexpr size_t SZ_WREC  = (size_t)2 * 3072 * HH * 2;
constexpr size_t OFF_BIAS = OFF_WREC + SZ_WREC;      // f32 [6144]
constexpr size_t SZ_BIAS  = (size_t)NCOL * 4;
// h tiles: [dir][buf][bg][jg(64)][b16(16)][j16(16)] bf16 — 512 B per tile
constexpr size_t OFF_H    = OFF_BIAS + SZ_BIAS;
constexpr size_t SZ_H     = (size_t)2 * 2 * 2 * 64 * 512;
constexpr size_t OFF_BAR  = OFF_H + SZ_H;            // flags [4 groups][64 jg][4 wave]
constexpr size_t SZ_BAR   = 4096;
// G layout: [s][dir][jg(64)][bg(2)][b16(16)][gate(3)][j(16)] bf16
constexpr size_t OFF_G    = OFF_BAR + SZ_BAR;
constexpr size_t SZ_G     = (size_t)SS * BB * NCOL * 2;
constexpr size_t WS_NEED  = OFF_G + SZ_G;            // ~455 MB

// gru_rec LDS layout
constexpr int WL_OFF = 0;          // 98304  weights
constexpr int PL_OFF = 98304;      // 26112  partials x2 parity
constexpr int GR_OFF = 124416;     // 6144   G ring, 4 slots x 1536B
constexpr int PF_OFF = 130560;     // 32     partial flags [2 par][4 wave]
constexpr int RD_OFF = 130592;     // 16     G ring ready[4]
constexpr int PG_OFF = 130608;     // 16     G ring progress[4 wave]
constexpr int SMEM_TOT = 130624;
constexpr int PLF = 4 * 3 * 16 * 17;   // floats per parity buffer

// =====================================================================
// prep
// =====================================================================
__global__ void prep_kernel(
    const float* __restrict__ x,
    const float* __restrict__ Wi, const float* __restrict__ Wni,
    const float* __restrict__ Winvi, const float* __restrict__ Wninvi,
    const float* __restrict__ Wh, const float* __restrict__ Wnh,
    const float* __restrict__ Winvh, const float* __restrict__ Wninvh,
    const float* __restrict__ Bg, const float* __restrict__ Bni,
    const float* __restrict__ Binv, const float* __restrict__ Bninvi,
    unsigned short* __restrict__ xb, unsigned short* __restrict__ WinT,
    unsigned short* __restrict__ Wrec, float* __restrict__ bias)
{
    constexpr int NX8  = (BB * SS * II) / 8;
    constexpr int NWI8 = (NCOL * II) / 8;
    constexpr int NWR8 = (2 * 3072 * HH) / 8;
    constexpr int TOT  = NX8 + NWI8 + NWR8 + NCOL;
    for (int i = blockIdx.x * blockDim.x + threadIdx.x; i < TOT;
         i += gridDim.x * blockDim.x) {
        if (i < NX8) {
            const float* sp = x + (size_t)i * 8;
            unsigned short o[8];
#pragma unroll
            for (int j = 0; j < 8; ++j) o[j] = f2bf(sp[j]);
            *(u4v*)(xb + (size_t)i * 8) = pack8(o);
        } else if (i < NX8 + NWI8) {
            int u = i - NX8;
            int n = u >> 6, k0 = (u & 63) * 8;
            const float* src; int stride;
            if (n < 2048)      { src = Wi + n;            stride = 2048; }
            else if (n < 3072) { src = Wni + (n - 2048);  stride = 1024; }
            else if (n < 5120) { src = Winvi + (n - 3072); stride = 2048; }
            else               { src = Wninvi + (n - 5120); stride = 1024; }
            unsigned short o[8];
#pragma unroll
            for (int j = 0; j < 8; ++j) o[j] = f2bf(src[(size_t)(k0 + j) * stride]);
            *(u4v*)(WinT + (size_t)n * 512 + k0) = pack8(o);
        } else if (i < NX8 + NWI8 + NWR8) {
            int u = i - NX8 - NWI8;
            int R = u >> 7, k0 = (u & 127) * 8;
            int dir = R / 3072, n = R % 3072;
            const float* src; int stride;
            if (n < 2048) { src = (dir ? Winvh : Wh) + n;          stride = 2048; }
            else          { src = (dir ? Wninvh : Wnh) + (n - 2048); stride = 1024; }
            unsigned short o[8];
#pragma unroll
            for (int j = 0; j < 8; ++j) o[j] = f2bf(src[(size_t)(k0 + j) * stride]);
            *(u4v*)(Wrec + (size_t)R * 1024 + k0) = pack8(o);
        } else {
            int c = i - NX8 - NWI8 - NWR8;
            int dir = c / 3072, cc = c % 3072;
            bias[c] = (cc < 2048) ? (dir ? Binv : Bg)[cc]
                                  : (dir ? Bninvi : Bni)[cc - 2048];
        }
    }
}

// =====================================================================
// gemm_in (best-measured r5/r7 version, single-buffered)
// =====================================================================
#define GLL16(gp, lp) __builtin_amdgcn_global_load_lds( \
    (const __attribute__((address_space(1))) void*)(gp), \
    (__attribute__((address_space(3))) void*)(lp), 16, 0, 0)

__global__ __launch_bounds__(256, 2) void gemm_in(
    const unsigned short* __restrict__ xb,
    const unsigned short* __restrict__ WinT,
    const float* __restrict__ bias,
    unsigned short* __restrict__ G)
{
    __shared__ char smem[32768];
    char* As = smem;
    char* Bs = smem + 16384;
    const int tid = threadIdx.x, lane = tid & 63, wid = tid >> 6;
    int wg = blockIdx.x;
    int swz = (wg & 7) * 1536 + (wg >> 3);
    const int m0 = (swz & 255) * 128, n0 = (swz >> 8) * 128;
    const int l15 = lane & 15, hi = lane >> 4;
    const int mw = (wid & 1) * 64, nw = (wid >> 1) * 64;

    f4v acc[4][4] = {};

    const char* xrow = (const char*)xb;
    const char* wrow = (const char*)WinT;

    for (int kt = 0; kt < 8; ++kt) {
        const int kb0 = kt * 128;
#pragma unroll
        for (int r = 0; r < 4; ++r) {
            int q = wid * 4 + r;
            int o = q * 1024 + lane * 16;
            int row = o >> 7;
            int kbs = (o ^ ((row & 7) << 4)) & 127;
            GLL16(xrow + (size_t)(m0 + row) * 1024 + kb0 + kbs, As + q * 1024);
            GLL16(wrow + (size_t)(n0 + row) * 1024 + kb0 + kbs, Bs + q * 1024);
        }
        __syncthreads();
#pragma unroll
        for (int kc = 0; kc < 2; ++kc) {
            s8v a[4], b[4];
#pragma unroll
            for (int mt = 0; mt < 4; ++mt) {
                int row = mw + mt * 16 + l15;
                int off = (row << 7) + kc * 64 + hi * 16;
                a[mt] = *(const s8v*)(As + (off ^ ((row & 7) << 4)));
            }
#pragma unroll
            for (int nt = 0; nt < 4; ++nt) {
                int row = nw + nt * 16 + l15;
                int off = (row << 7) + kc * 64 + hi * 16;
                b[nt] = *(const s8v*)(Bs + (off ^ ((row & 7) << 4)));
            }
#pragma unroll
            for (int mt = 0; mt < 4; ++mt)
#pragma unroll
                for (int nt = 0; nt < 4; ++nt)
                    acc[mt][nt] = __builtin_amdgcn_mfma_f32_16x16x32_bf16(
                        a[mt], b[nt], acc[mt][nt], 0, 0, 0);
        }
        __syncthreads();
    }
#pragma unroll
    for (int mt = 0; mt < 4; ++mt) {
#pragma unroll
        for (int rg = 0; rg < 4; ++rg) {
            int m = m0 + mw + mt * 16 + hi * 4 + rg;
            int bi = m >> 10, si = m & 1023;
            int bg = bi >> 4, b16 = bi & 15;
#pragma unroll
            for (int nt = 0; nt < 4; ++nt) {
                int n = n0 + nw + nt * 16 + l15;
                int dir = (n >= 3072);
                int rem = n - dir * 3072;
                int gate = rem >> 10, col = rem & 1023;
                int jg = col >> 4, j = col & 15;
                size_t idx = (((((size_t)si * 2 + dir) * 64 + jg) * 2 + bg) * 16
                              + b16) * 48 + gate * 16 + j;
                G[idx] = f2bf(acc[mt][nt][rg] + bias[n]);
            }
        }
    }
}

// =====================================================================
// gru_rec: best-measured structure (r5) + pipelined double-poll spin.
// 256 blocks (1/CU), 320 threads: waves 0-3 compute, wave 4 = G prefetch.
// =====================================================================
__global__ __launch_bounds__(320, 1) void gru_rec(
    const unsigned short* __restrict__ G,     // [s][dir][jg][bg][b16][gate][j]
    const unsigned short* __restrict__ Wrec,  // [2][3072][1024]
    const float* __restrict__ Bnh,
    const float* __restrict__ Bninvh,
    unsigned short* __restrict__ hbuf,        // bf16 tiles [dir][buf][bg][jg][16][16]
    float* __restrict__ out,                  // [32][1024][2048] + ht [32][2048]
    unsigned int* __restrict__ flags)         // [4 groups][64 jg][4 wave]
{
    extern __shared__ char smem[];
    char* wl = smem + WL_OFF;
    float* pl = (float*)(smem + PL_OFF);
    unsigned short* gring = (unsigned short*)(smem + GR_OFF);
    volatile int* pflag = (volatile int*)(smem + PF_OFF);
    volatile int* gready = (volatile int*)(smem + RD_OFF);
    volatile int* gprog  = (volatile int*)(smem + PG_OFF);

    const int tid = threadIdx.x, lane = tid & 63, wid = tid >> 6;
    const int bid = blockIdx.x;
    const int dir = bid >> 7, bg = (bid >> 6) & 1, jg = bid & 63;
    const int jbase = jg * 16, bb = bg * 16;
    const int l15 = lane & 15, hi = lane >> 4;
    unsigned int* fl = flags + ((dir * 2 + bg) << 8);

    // ---- prologue: init LDS flags; stage 3 weight panels into LDS ----
    if (tid < 4) { gready[tid] = -1; gprog[tid] = -1; }
    if (tid >= 4 && tid < 12) pflag[tid - 4] = -1;
    if (tid < 256) {
        const char* wsrc = (const char*)Wrec;
        for (int q = 0; q < 24; ++q) {
            int o = (q * 256 + tid) * 16;
            int c = o >> 11;
            int kb = (o ^ ((c & 7) << 4)) & 2047;
            int n = dir * 3072 + (c >> 4) * 1024 + jbase + (c & 15);
            *(u4v*)(wl + o) = *(const u4v*)(wsrc + (size_t)n * 2048 + kb);
        }
    }
    const int b_l = tid >> 4, j_l = tid & 15;
    const float bnh = (dir ? Bninvh : Bnh)[jbase + (j_l & 15)];
    __syncthreads();   // the ONLY block-wide barrier

    const size_t gstride_b = (size_t)2 * 64 * 2 * 768 * 2;   // bytes per s
    const char* gcb = (const char*)G + (((size_t)dir * 64 + jg) * 2 + bg) * 1536;

    if (wid == 4) {
        // ---------------- G prefetch wave ----------------
        char* grb = (char*)gring;
        for (int t = 0; t < 1024; ++t) {
            const int slot = t & 3;
            if (t >= 4) {
                int v;
                do { v = gprog[lane & 3]; } while (!__all(v >= t - 4));
            }
            const int gpos = dir ? (1023 - t) : t;
            const char* src = gcb + (size_t)gpos * gstride_b + lane * 32;
            if (lane < 48) {
                u4v d0 = *(const u4v*)(src);
                u4v d1 = *(const u4v*)(src + 16);
                *(u4v*)(grb + slot * 1536 + lane * 32) = d0;
                *(u4v*)(grb + slot * 1536 + lane * 32 + 16) = d1;
            }
            asm volatile("s_waitcnt lgkmcnt(0) vmcnt(0)" ::: "memory");
            if (lane == 0) gready[slot] = t;
        }
        return;
    }

    // ---------------- compute waves (0..3) ----------------
    float h_old = 0.0f;
    unsigned int* hbuf32 = (unsigned int*)hbuf;
    // targeted poll: wave wid reads blocks [wid*16, wid*16+16) — their 64 flags
    const unsigned int* fp = fl + wid * 64 + lane;

    for (int s = 0; s < 1024; ++s) {
        const int par = s & 1;
        float* plc = pl + par * PLF;

        // ---- G for this step from the LDS ring ----
        const int slot = s & 3;
        {
            int r;
            do { r = gready[slot]; } while (r != s);
        }
        asm volatile("" ::: "memory");
        const int gb = slot * 768 + b_l * 48 + j_l;
        unsigned short gr = gring[gb];
        unsigned short gz = gring[gb + 16];
        unsigned short gn = gring[gb + 32];
        asm volatile("s_waitcnt lgkmcnt(0)" ::: "memory");
        if (lane == 0) gprog[wid] = s;

        float rsum = 0.f, zsum = 0.f, nsum = 0.f;
        if (s > 0) {
            // ---- pipelined double-poll spin (RT/2 detect granularity) ----
            const unsigned tgt = (unsigned)s;
            unsigned va, vb;
            poll_issue(fp, va);
            for (;;) {
                poll_issue(fp, vb);
                asm volatile("s_waitcnt vmcnt(1)" : "+v"(va) :: "memory");
                if (__all(va >= tgt)) break;
                poll_issue(fp, va);
                asm volatile("s_waitcnt vmcnt(1)" : "+v"(vb) :: "memory");
                if (__all(vb >= tgt)) break;
            }
            // ≤1 stray poll load in flight; va/vb pinned through the gather,
            // whose trailing vmcnt(0) drains it concurrently with the data.

            // ---- gather h tiles (contiguous 512B per producer block) ----
            const int rbuf = par ^ 1;
            const char* hb = (const char*)hbuf +
                ((((size_t)(dir * 2 + rbuf) * 2 + bg) * 64)
                 + (size_t)(wid * 16 + (hi >> 1))) * 512
                + l15 * 32 + (hi & 1) * 16;
            u4v u[8];
            gather_h(hb, hb + 4096, u[0], u[1], u[2], u[3],
                     u[4], u[5], u[6], u[7], va, vb);

            f4v acc[3] = {};
#pragma unroll
            for (int p = 0; p < 3; ++p) {
                int c = p * 16 + l15;
                int cbase = c << 11;
                int sw = (c & 7) << 4;
#pragma unroll
                for (int kc = 0; kc < 8; ++kc) {
                    int off = cbase + (wid << 9) + kc * 64 + hi * 16;
                    s8v bf = *(const s8v*)(wl + (off ^ sw));
                    acc[p] = __builtin_amdgcn_mfma_f32_16x16x32_bf16(
                        __builtin_bit_cast(s8v, u[kc]), bf, acc[p], 0, 0, 0);
                }
            }
#pragma unroll
            for (int p = 0; p < 3; ++p)
#pragma unroll
                for (int rg = 0; rg < 4; ++rg)
                    plc[((wid * 3 + p) * 16 + hi * 4 + rg) * 17 + l15] = acc[p][rg];
            asm volatile("s_waitcnt lgkmcnt(0)" ::: "memory");
            if (lane == 0) pflag[par * 4 + wid] = s;

            // ---- barrier-free reduce sync: wait all 4 compute waves ----
            {
                int f0, f1, f2, f3;
                do {
                    f0 = pflag[par * 4 + 0]; f1 = pflag[par * 4 + 1];
                    f2 = pflag[par * 4 + 2]; f3 = pflag[par * 4 + 3];
                } while (f0 < s || f1 < s || f2 < s || f3 < s);
            }
            asm volatile("" ::: "memory");
#pragma unroll
            for (int w = 0; w < 4; ++w) {
                rsum += plc[((w * 3 + 0) * 16 + b_l) * 17 + j_l];
                zsum += plc[((w * 3 + 1) * 16 + b_l) * 17 + j_l];
                nsum += plc[((w * 3 + 2) * 16 + b_l) * 17 + j_l];
            }
        }

        float rv = sigm(rsum + bf2f(gr));
        float zv = sigm(zsum + bf2f(gz));
        float nv = tanh_fast(bf2f(gn) + rv * (nsum + bnh));
        float hn = (1.0f - zv) * nv + zv * h_old;
        h_old = hn;

        // h tile store: contiguous 512B, write-through pairs
        if (s < 1023) {
            unsigned short hbv = f2bf(hn);
            unsigned int other = (unsigned int)(unsigned short)__shfl_xor((int)hbv, 1);
            if (!(tid & 1)) {
                size_t w32 = ((((size_t)(dir * 2 + par) * 2 + bg) * 64 + jg) * 128)
                             + b_l * 8 + (j_l >> 1);
                store_wt(hbuf32 + w32, (unsigned)hbv | (other << 16));
            }
        }
        // out: plain cached store (L2 ack, inside the drain — best-measured r5 tail)
        const int s_out = dir ? (1023 - s) : s;
        out[((size_t)(bb + b_l) * SS + s_out) * 2048 + dir * 1024 + jbase + j_l] = hn;
        if (s == 1023)
            out[(size_t)BB * SS * 2048 + (size_t)(bb + b_l) * 2048 +
                dir * 1024 + jbase + j_l] = hn;

        if (s < 1023) {
            // drain this wave's stores, then publish its flag
            asm volatile("s_waitcnt vmcnt(0)" ::: "memory");
            if (lane == 0)
                store_wt(&fl[jg * 4 + wid], (unsigned)(s + 1));
        }
    }
}

// =====================================================================
extern "C" void kernel_launch(void* const* d_in, const int* in_sizes, int n_in,
                              void* d_out, int out_size, void* d_ws, size_t ws_size,
                              hipStream_t stream)
{
    if (n_in < 15) return;
    const float* x      = (const float*)d_in[0];
    const float* Wi     = (const float*)d_in[1];
    const float* Wh     = (const float*)d_in[2];
    const float* Bg     = (const float*)d_in[3];
    const float* Wni    = (const float*)d_in[4];
    const float* Wnh    = (const float*)d_in[5];
    const float* Bni    = (const float*)d_in[6];
    const float* Bnh    = (const float*)d_in[7];
    const float* Winvi  = (const float*)d_in[8];
    const float* Winvh  = (const float*)d_in[9];
    const float* Binv   = (const float*)d_in[10];
    const float* Wninvi = (const float*)d_in[11];
    const float* Wninvh = (const float*)d_in[12];
    const float* Bninvi = (const float*)d_in[13];
    const float* Bninvh = (const float*)d_in[14];

    if (ws_size < WS_NEED) {
        hipMemsetAsync(d_out, 0, (size_t)out_size * 4, stream);
        return;
    }
    char* ws = (char*)d_ws;
    unsigned short* xb   = (unsigned short*)(ws + OFF_X);
    unsigned short* WinT = (unsigned short*)(ws + OFF_WINT);
    unsigned short* Wrec = (unsigned short*)(ws + OFF_WREC);
    float*          bias = (float*)(ws + OFF_BIAS);
    unsigned short* hbuf = (unsigned short*)(ws + OFF_H);
    unsigned int*   bar  = (unsigned int*)(ws + OFF_BAR);
    unsigned short* G    = (unsigned short*)(ws + OFF_G);

    hipMemsetAsync(ws + OFF_BAR, 0, SZ_BAR, stream);

    prep_kernel<<<4096, 256, 0, stream>>>(
        x, Wi, Wni, Winvi, Wninvi, Wh, Wnh, Winvh, Wninvh,
        Bg, Bni, Binv, Bninvi, xb, WinT, Wrec, bias);

    gemm_in<<<12288, 256, 0, stream>>>(xb, WinT, bias, G);

    hipFuncSetAttribute(reinterpret_cast<const void*>(&gru_rec),
                        hipFuncAttributeMaxDynamicSharedMemorySize, SMEM_TOT);
    gru_rec<<<256, 320, SMEM_TOT, stream>>>(
        G, Wrec, Bnh, Bninvh, hbuf, (float*)d_out, bar);
}